// Round 1
// baseline (436.306 us; speedup 1.0000x reference)
//
#include <hip/hip_runtime.h>
#include <hip/hip_bf16.h>
#include <stdint.h>

// MoE routed GEMM: out[i] = x[i] @ W[e_i] + b[e_i]
// B=8192, D=2048, E=8. fp32 in/out, bf16 MFMA compute.
// R4: (a) gather pass DELETED -- gemm stages A via perm-indexed per-lane
//     global_load_lds sources from unsorted bf16 xb (same 64B/row segments
//     either way, so zero coalescing loss); (b) route+xconv+wt merged into
//     ONE k_prep kernel (route = block 0, hidden under BW work); (c) gemm
//     rebuilt as 256x256 2-phase double-buffered pipeline (BK=64, 512 thr,
//     1 barrier/K-step, prefetch issued before compute) with rule-#21
//     source-side XOR swizzle -> conflict-free ds_read_b128.

#define B_TOK 8192
#define DIM   2048
#define NEXP  8
#define BM 256
#define BN 256
#define BK 64

typedef __attribute__((ext_vector_type(4))) float f32x4;
typedef __attribute__((ext_vector_type(8))) short s16x8;

// RNE float->bf16
__device__ __forceinline__ uint32_t f2bf(float f) {
    uint32_t u = __float_as_uint(f);
    uint32_t r = u + 0x7fffu + ((u >> 16) & 1u);
    return r >> 16;
}

__device__ __forceinline__ void async16(const void* g, void* l) {
    __builtin_amdgcn_global_load_lds(
        (const __attribute__((address_space(1))) uint32_t*)g,
        (__attribute__((address_space(3))) uint32_t*)l, 16, 0, 0);
}

// ---- prep: block 0 = routing; blocks 1..8192 = x fp32->bf16 (unsorted);
// ---- blocks 8193..12288 = W[e][d][o] -> Wt[e][o][d] bf16 transpose.
__global__ __launch_bounds__(256) void k_prep(const float* __restrict__ x,
                                              const float* __restrict__ W,
                                              const int* __restrict__ idx,
                                              int* __restrict__ meta,
                                              int* __restrict__ perm,
                                              uint16_t* __restrict__ xb,
                                              uint16_t* __restrict__ Wt) {
    __shared__ __align__(16) char smem[16640];   // max(route 9252, wt 16640)
    int bid = blockIdx.x;
    int t = threadIdx.x;

    if (bid == 0) {
        // ---- routing: zero atomics, deterministic (unchanged logic) ----
        int (*cnt)[9] = (int(*)[9])smem;          // 256*9*4 = 9216
        int* offS = (int*)(smem + 9216);          // 9*4
        int myIdx[32];
        #pragma unroll
        for (int i = 0; i < 32; ++i) myIdx[i] = idx[t * 32 + i];
        int c[NEXP] = {0, 0, 0, 0, 0, 0, 0, 0};
        #pragma unroll
        for (int i = 0; i < 32; ++i) {
            int e = myIdx[i];
            #pragma unroll
            for (int k = 0; k < NEXP; ++k) c[k] += (e == k) ? 1 : 0;
        }
        #pragma unroll
        for (int k = 0; k < NEXP; ++k) cnt[t][k] = c[k];
        __syncthreads();
        if (t < NEXP) {                 // 8 threads: exclusive scan down column t
            int run = 0;
            for (int j = 0; j < 256; ++j) { int v = cnt[j][t]; cnt[j][t] = run; run += v; }
            offS[t] = run;
        }
        __syncthreads();
        if (t == 0) {
            int off = 0;
            #pragma unroll
            for (int e = 0; e < NEXP; ++e) {
                int v = offS[e];
                offS[e] = off; meta[16 + e] = off; off += v;
            }
            offS[NEXP] = off; meta[16 + NEXP] = off;
        }
        __syncthreads();
        int base[NEXP];
        #pragma unroll
        for (int k = 0; k < NEXP; ++k) base[k] = offS[k] + cnt[t][k];
        #pragma unroll
        for (int i = 0; i < 32; ++i) {
            int e = myIdx[i];
            int pos = 0;
            #pragma unroll
            for (int k = 0; k < NEXP; ++k) pos += (e == k) ? base[k] : 0;
            perm[pos] = t * 32 + i;
            #pragma unroll
            for (int k = 0; k < NEXP; ++k) base[k] += (e == k) ? 1 : 0;
        }
        return;
    }

    if (bid <= B_TOK) {
        // ---- x convert, original row order (no perm dependency) ----
        int p = bid - 1;
        const float4* xin = (const float4*)(x + (size_t)p * DIM);
        float4 a = xin[2 * t];
        float4 c = xin[2 * t + 1];
        uint4 o;
        o.x = f2bf(a.x) | (f2bf(a.y) << 16);
        o.y = f2bf(a.z) | (f2bf(a.w) << 16);
        o.z = f2bf(c.x) | (f2bf(c.y) << 16);
        o.w = f2bf(c.z) | (f2bf(c.w) << 16);
        *(uint4*)(xb + (size_t)p * DIM + t * 8) = o;
        return;
    }

    // ---- W transpose tile 128d x 64o (unchanged logic) ----
    int wb = bid - (B_TOK + 1);
    int bx = wb & 15, by = (wb >> 4) & 31, e = wb >> 9;
    int d0 = bx * 128, o0 = by * 64;
    uint32_t (*lds)[65] = (uint32_t(*)[65])smem;
    const float* Wp = W + ((size_t)e * DIM + d0) * DIM + o0;
    #pragma unroll
    for (int p = 0; p < 4; ++p) {
        int dp = p * 16 + (t >> 4);      // d-pair index 0..63
        int oc = (t & 15) * 4;           // o base
        const float* r0 = Wp + (size_t)(2 * dp) * DIM + oc;
        float4 v0 = *(const float4*)r0;
        float4 v1 = *(const float4*)(r0 + DIM);
        lds[oc + 0][dp ^ (((oc + 0) & 15) << 2)] = f2bf(v0.x) | (f2bf(v1.x) << 16);
        lds[oc + 1][dp ^ (((oc + 1) & 15) << 2)] = f2bf(v0.y) | (f2bf(v1.y) << 16);
        lds[oc + 2][dp ^ (((oc + 2) & 15) << 2)] = f2bf(v0.z) | (f2bf(v1.z) << 16);
        lds[oc + 3][dp ^ (((oc + 3) & 15) << 2)] = f2bf(v0.w) | (f2bf(v1.w) << 16);
    }
    __syncthreads();
    uint16_t* Wo = Wt + ((size_t)e * DIM + o0) * DIM + d0;
    #pragma unroll
    for (int q = 0; q < 4; ++q) {
        int o = q * 16 + (t >> 4);
        int cb = ((t & 15) * 4) ^ ((o & 15) << 2);
        uint4 w = *(const uint4*)&lds[o][cb];
        *(uint4*)(Wo + (size_t)o * DIM + (t & 15) * 8) = w;
    }
}

// ---- per-expert-segment GEMM: 256x256 tile, BK=64, 2-phase dbuf ---------
// 512 thr = 8 waves (2M x 4N), per-wave 128x64 output. LDS 129KB ->
// 1 block/CU. One barrier per K-step; next tile's global_load_lds issued
// before ds_read+MFMA so HBM latency hides under 64 MFMAs.
// Swizzle (rule #21): source sub-chunk kc = ((ch&7)^(row&7))*8 at stage,
// slot ((s*4+quad)^(lr&7)) at read -> 2-way max bank aliasing (free).
__global__ __launch_bounds__(512, 2) void k_gemm(
    const uint16_t* __restrict__ xb, const uint16_t* __restrict__ Wt,
    const float* __restrict__ bias, const int* __restrict__ meta,
    const int* __restrict__ perm, float* __restrict__ out) {
    __shared__ uint16_t As[2][BM * BK];   // 2 x 32KB
    __shared__ uint16_t Bs[2][BN * BK];   // 2 x 32KB
    __shared__ int permS[BM];

    int id = blockIdx.y;
    int e = -1, seg0 = 0, segc = 0;
    for (int i = 0; i < NEXP; ++i) {
        int o0 = meta[16 + i], o1 = meta[16 + i + 1];
        int tiles = (o1 - o0 + BM - 1) / BM;
        if (id < tiles) { e = i; seg0 = o0; segc = o1 - o0; break; }
        id -= tiles;
    }
    if (e < 0) return;
    int m0 = seg0 + id * BM;
    int valid = segc - id * BM; if (valid > BM) valid = BM;
    int n0 = blockIdx.x * BN;

    int tid = threadIdx.x;
    if (tid < BM) permS[tid] = (tid < valid) ? perm[m0 + tid] : 0;

    int wave = tid >> 6, lane = tid & 63;
    int wm = (wave >> 2) * 128, wn = (wave & 3) * 64;
    int lr = lane & 15, quad = lane >> 4;

    // per-thread staging sources (4 A-chunks + 4 B-chunks of 16B), hoisted.
    // chunk ch = c*512+tid: row = ch>>3 (0..255), source sub-chunk XOR'd.
    const uint16_t* aSrc[4];
    const uint16_t* bSrc[4];
    #pragma unroll
    for (int c = 0; c < 4; ++c) {
        int ch = c * 512 + tid;
        int row = ch >> 3;
        int kc = ((ch & 7) ^ (row & 7)) * 8;
        int pr = m0 + row; if (pr > B_TOK - 1) pr = B_TOK - 1;  // clamp: tail rows masked at store
        aSrc[c] = xb + (size_t)perm[pr] * DIM + kc;
        bSrc[c] = Wt + ((size_t)e * DIM + n0 + row) * DIM + kc;
    }

    auto STAGE = [&](int buf, int k0) {
        #pragma unroll
        for (int c = 0; c < 4; ++c) {
            int ch = c * 512 + tid;
            async16(aSrc[c] + k0, &As[buf][ch * 8]);
            async16(bSrc[c] + k0, &Bs[buf][ch * 8]);
        }
    };

    f32x4 acc[8][4] = {};
    STAGE(0, 0);
    __syncthreads();

    int cur = 0;
    int sw = lr & 7;
    for (int k0 = 0; k0 < DIM; k0 += BK) {
        if (k0 + BK < DIM) STAGE(cur ^ 1, k0 + BK);   // prefetch overlaps compute
        #pragma unroll
        for (int s = 0; s < 2; ++s) {
            s16x8 af[8], bfr[4];
            #pragma unroll
            for (int i = 0; i < 8; ++i)
                af[i] = *(const s16x8*)&As[cur][(wm + i * 16 + lr) * BK + (((s * 4 + quad) ^ sw) * 8)];
            #pragma unroll
            for (int j = 0; j < 4; ++j)
                bfr[j] = *(const s16x8*)&Bs[cur][(wn + j * 16 + lr) * BK + (((s * 4 + quad) ^ sw) * 8)];
            #pragma unroll
            for (int i = 0; i < 8; ++i)
                #pragma unroll
                for (int j = 0; j < 4; ++j)
                    acc[i][j] = __builtin_amdgcn_mfma_f32_16x16x32_bf16(af[i], bfr[j], acc[i][j], 0, 0, 0);
        }
        __syncthreads();   // drains vmcnt (stage of cur^1 done) + lgkm
        cur ^= 1;
    }

    #pragma unroll
    for (int j = 0; j < 4; ++j) {
        int col = n0 + wn + j * 16 + lr;
        float bv = bias[e * DIM + col];
        #pragma unroll
        for (int i = 0; i < 8; ++i) {
            #pragma unroll
            for (int r = 0; r < 4; ++r) {
                int lrow = wm + i * 16 + quad * 4 + r;
                if (lrow < valid) {
                    out[(size_t)permS[lrow] * DIM + col] = acc[i][j][r] + bv;
                }
            }
        }
    }
}

// ---- launch --------------------------------------------------------------
// ws: [0,256) meta | [256,33024) perm | [64K, +33.55MB) xb (bf16, unsorted,
// no pad needed: A sources are perm-clamped to valid rows) | Wt 67.1MB.
// Total ~96.1 MiB (was ~96.6).
extern "C" void kernel_launch(void* const* d_in, const int* in_sizes, int n_in,
                              void* d_out, int out_size, void* d_ws, size_t ws_size,
                              hipStream_t stream) {
    const float* x    = (const float*)d_in[0];
    const float* W    = (const float*)d_in[1];
    const float* bias = (const float*)d_in[2];
    const int*   idx  = (const int*)d_in[3];
    float* out = (float*)d_out;

    char* ws = (char*)d_ws;
    int* meta = (int*)ws;
    int* perm = (int*)(ws + 256);
    uint16_t* xb = (uint16_t*)(ws + 65536);
    uint16_t* Wt = (uint16_t*)(ws + 65536 + (size_t)B_TOK * DIM * 2);

    // 1 route block + 8192 xconv blocks + 4096 wt blocks, all independent.
    k_prep<<<1 + B_TOK + 4096, 256, 0, stream>>>(x, W, idx, meta, perm, xb, Wt);
    k_gemm<<<dim3(DIM / BN, B_TOK / BM + NEXP, 1), 512, 0, stream>>>(
        xb, Wt, bias, meta, perm, out);
}

// Round 2
// 397.819 us; speedup vs baseline: 1.0967x; 1.0967x over previous
//
#include <hip/hip_runtime.h>
#include <hip/hip_bf16.h>
#include <stdint.h>

// MoE routed GEMM: out[i] = x[i] @ W[e_i] + b[e_i]
// B=8192, D=2048, E=8. fp32 in/out, bf16 MFMA compute.
// R5: GEMM rebuilt as the 8-phase counted-vmcnt schedule (T3+T4+T5):
//   - BM=BN=256, BK=64 processed as two K-sub-32 halves; per phase: stage
//     exactly one 16KB half (2 global_load_lds/thread), vmcnt(6) at odd
//     phases ONLY (derived: each half restaged exactly 2 phases after its
//     last read; 3 halves in flight), two raw s_barriers + lgkmcnt(0) per
//     phase, setprio(1) around the 16-MFMA cluster. No vmcnt(0) in loop.
//   - LDS 256-row x 32-elem halves, slot swizzle s^= (row>>1)&3 applied on
//     the per-lane GLOBAL source (rule #21) -> conflict-free ds_read_b128.
//   - full tiles enumerated FIRST (XCD-chunked bijective map), partial
//     tiles last with wave-uniform M-frag skip -> round 2 is cheap.
// k_prep unchanged from R4 (route block 0 + x->bf16 + W transpose).

#define B_TOK 8192
#define DIM   2048
#define NEXP  8
#define BM 256
#define BN 256
#define BK 64

typedef __attribute__((ext_vector_type(4))) float f32x4;
typedef __attribute__((ext_vector_type(8))) short s16x8;

// RNE float->bf16
__device__ __forceinline__ uint32_t f2bf(float f) {
    uint32_t u = __float_as_uint(f);
    uint32_t r = u + 0x7fffu + ((u >> 16) & 1u);
    return r >> 16;
}

__device__ __forceinline__ void async16(const void* g, void* l) {
    __builtin_amdgcn_global_load_lds(
        (const __attribute__((address_space(1))) uint32_t*)g,
        (__attribute__((address_space(3))) uint32_t*)l, 16, 0, 0);
}

// ---- prep: block 0 = routing; blocks 1..8192 = x fp32->bf16 (unsorted);
// ---- blocks 8193..12288 = W[e][d][o] -> Wt[e][o][d] bf16 transpose.
__global__ __launch_bounds__(256) void k_prep(const float* __restrict__ x,
                                              const float* __restrict__ W,
                                              const int* __restrict__ idx,
                                              int* __restrict__ meta,
                                              int* __restrict__ perm,
                                              uint16_t* __restrict__ xb,
                                              uint16_t* __restrict__ Wt) {
    __shared__ __align__(16) char smem[16640];   // max(route 9252, wt 16640)
    int bid = blockIdx.x;
    int t = threadIdx.x;

    if (bid == 0) {
        // ---- routing: zero atomics, deterministic ----
        int (*cnt)[9] = (int(*)[9])smem;          // 256*9*4 = 9216
        int* offS = (int*)(smem + 9216);          // 9*4
        int myIdx[32];
        #pragma unroll
        for (int i = 0; i < 32; ++i) myIdx[i] = idx[t * 32 + i];
        int c[NEXP] = {0, 0, 0, 0, 0, 0, 0, 0};
        #pragma unroll
        for (int i = 0; i < 32; ++i) {
            int e = myIdx[i];
            #pragma unroll
            for (int k = 0; k < NEXP; ++k) c[k] += (e == k) ? 1 : 0;
        }
        #pragma unroll
        for (int k = 0; k < NEXP; ++k) cnt[t][k] = c[k];
        __syncthreads();
        if (t < NEXP) {                 // 8 threads: exclusive scan down column t
            int run = 0;
            for (int j = 0; j < 256; ++j) { int v = cnt[j][t]; cnt[j][t] = run; run += v; }
            offS[t] = run;
        }
        __syncthreads();
        if (t == 0) {
            int off = 0;
            #pragma unroll
            for (int e = 0; e < NEXP; ++e) {
                int v = offS[e];
                offS[e] = off; meta[16 + e] = off; off += v;
            }
            offS[NEXP] = off; meta[16 + NEXP] = off;
        }
        __syncthreads();
        int base[NEXP];
        #pragma unroll
        for (int k = 0; k < NEXP; ++k) base[k] = offS[k] + cnt[t][k];
        #pragma unroll
        for (int i = 0; i < 32; ++i) {
            int e = myIdx[i];
            int pos = 0;
            #pragma unroll
            for (int k = 0; k < NEXP; ++k) pos += (e == k) ? base[k] : 0;
            perm[pos] = t * 32 + i;
            #pragma unroll
            for (int k = 0; k < NEXP; ++k) base[k] += (e == k) ? 1 : 0;
        }
        return;
    }

    if (bid <= B_TOK) {
        // ---- x convert, original row order ----
        int p = bid - 1;
        const float4* xin = (const float4*)(x + (size_t)p * DIM);
        float4 a = xin[2 * t];
        float4 c = xin[2 * t + 1];
        uint4 o;
        o.x = f2bf(a.x) | (f2bf(a.y) << 16);
        o.y = f2bf(a.z) | (f2bf(a.w) << 16);
        o.z = f2bf(c.x) | (f2bf(c.y) << 16);
        o.w = f2bf(c.z) | (f2bf(c.w) << 16);
        *(uint4*)(xb + (size_t)p * DIM + t * 8) = o;
        return;
    }

    // ---- W transpose tile 128d x 64o ----
    int wb = bid - (B_TOK + 1);
    int bx = wb & 15, by = (wb >> 4) & 31, e = wb >> 9;
    int d0 = bx * 128, o0 = by * 64;
    uint32_t (*lds)[65] = (uint32_t(*)[65])smem;
    const float* Wp = W + ((size_t)e * DIM + d0) * DIM + o0;
    #pragma unroll
    for (int p = 0; p < 4; ++p) {
        int dp = p * 16 + (t >> 4);      // d-pair index 0..63
        int oc = (t & 15) * 4;           // o base
        const float* r0 = Wp + (size_t)(2 * dp) * DIM + oc;
        float4 v0 = *(const float4*)r0;
        float4 v1 = *(const float4*)(r0 + DIM);
        lds[oc + 0][dp ^ (((oc + 0) & 15) << 2)] = f2bf(v0.x) | (f2bf(v1.x) << 16);
        lds[oc + 1][dp ^ (((oc + 1) & 15) << 2)] = f2bf(v0.y) | (f2bf(v1.y) << 16);
        lds[oc + 2][dp ^ (((oc + 2) & 15) << 2)] = f2bf(v0.z) | (f2bf(v1.z) << 16);
        lds[oc + 3][dp ^ (((oc + 3) & 15) << 2)] = f2bf(v0.w) | (f2bf(v1.w) << 16);
    }
    __syncthreads();
    uint16_t* Wo = Wt + ((size_t)e * DIM + o0) * DIM + d0;
    #pragma unroll
    for (int q = 0; q < 4; ++q) {
        int o = q * 16 + (t >> 4);
        int cb = ((t & 15) * 4) ^ ((o & 15) << 2);
        uint4 w = *(const uint4*)&lds[o][cb];
        *(uint4*)(Wo + (size_t)o * DIM + (t & 15) * 8) = w;
    }
}

// ---- 8-phase GEMM core ----------------------------------------------------
// LDS halves: As/Bs[buf][ksub][256 rows][32 elems] (16KB each).
// Read swizzle: phys 16B-slot = quad ^ ((row>>1)&3)  (2-way banks = free).
// Stage: linear LDS dest, source slot pre-swizzled per lane (rule #21).
// Phase rotation (p = tp*4+q; iter computes tiles 2i(buf0), 2i+1(buf1)):
//   compute: p0(m0k0) p1(m1k0) p2(m0k1) p3(m1k1) on buf tp
//   stage:   p0:A[1][1]@t+1k1  p1:B[1][1]  p2:A[0][0]@t+2k0 p3:B[0][0]
//            p4:A[0][1]@t+2k1  p5:B[0][1]  p6:A[1][0]@t+3k0 p7:B[1][0]
//   every half restaged exactly 2 phases after its last read; vmcnt(6) at
//   odd phases retires the half first read 1 phase later. No vmcnt(0).
template<bool FULL>
__device__ __forceinline__ void gemm_core(
    uint16_t (*As)[2][8192], uint16_t (*Bs)[2][8192], int* permS,
    const uint16_t* __restrict__ xb, const uint16_t* __restrict__ Wt,
    const float* __restrict__ bias, const int* __restrict__ perm,
    float* __restrict__ out, int e, int m0, int valid, int n0) {

    int tid = threadIdx.x;
    if (tid < BM) permS[tid] = (tid < valid) ? perm[m0 + tid] : 0;

    int wave = tid >> 6, lane = tid & 63;
    int wm = (wave >> 2) * 128, wn = (wave & 3) * 64;
    int lr = lane & 15, quad = lane >> 4;
    const int rdswz = (quad ^ ((lr >> 1) & 3)) * 8;   // element offset in row
    int nfw = 8;
    if (!FULL) { nfw = (valid > wm) ? ((valid - wm + 15) >> 4) : 0; if (nfw > 8) nfw = 8; }

    // staging sources: chunk ch = c*512+tid -> row = ch>>2, slot = ch&3;
    // source slot = slot ^ ((row>>1)&3) = (tid&3) ^ ((tid>>3)&3)  (both c).
    const int srcswz = (((tid & 3) ^ ((tid >> 3) & 3)) * 8);
    const uint16_t* aPtr[2];
    const uint16_t* bPtr[2];
    #pragma unroll
    for (int c = 0; c < 2; ++c) {
        int row = c * 128 + (tid >> 2);
        int ar = m0 + row; if (ar > B_TOK - 1) ar = B_TOK - 1;
        aPtr[c] = xb + (size_t)perm[ar] * DIM + srcswz;
        bPtr[c] = Wt + ((size_t)e * DIM + n0 + row) * DIM + srcswz;
    }

    auto stageA = [&](int buf, int h, int koff) {
        #pragma unroll
        for (int c = 0; c < 2; ++c)
            async16(aPtr[c] + koff, &As[buf][h][(c * 512 + tid) * 8]);
    };
    auto stageB = [&](int buf, int h, int koff) {
        #pragma unroll
        for (int c = 0; c < 2; ++c)
            async16(bPtr[c] + koff, &Bs[buf][h][(c * 512 + tid) * 8]);
    };

    f32x4 acc[8][4] = {};

    // prologue: tile0 k0,k1 + tile1 k0 (12 loads); need first 4 landed.
    stageA(0, 0, 0);  stageB(0, 0, 0);
    stageA(0, 1, 32); stageB(0, 1, 32);
    stageA(1, 0, 64); stageB(1, 0, 64);
    asm volatile("s_waitcnt vmcnt(8)" ::: "memory");
    __builtin_amdgcn_s_barrier();

    for (int it = 0; it < DIM / 128; ++it) {
        int t0 = 2 * it;
        #pragma unroll
        for (int tp = 0; tp < 2; ++tp) {
            s16x8 bfr[4];
            #pragma unroll
            for (int q = 0; q < 4; ++q) {
                const int p = tp * 4 + q;
                const int fh = q & 1, ks = q >> 1;
                if (p & 1) asm volatile("s_waitcnt vmcnt(6)" ::: "memory");
                // ds_read current fragments
                s16x8 af[4];
                #pragma unroll
                for (int ii = 0; ii < 4; ++ii)
                    af[ii] = *(const s16x8*)&As[tp][ks][(wm + (fh * 4 + ii) * 16 + lr) * 32 + rdswz];
                if (fh == 0) {
                    #pragma unroll
                    for (int j = 0; j < 4; ++j)
                        bfr[j] = *(const s16x8*)&Bs[tp][ks][(wn + j * 16 + lr) * 32 + rdswz];
                }
                // stage one half per rotation table
                {
                    int koff = (p == 0 || p == 1) ? (t0 + 1) * 64 + 32
                             : (p == 2 || p == 3) ? (t0 + 2) * 64
                             : (p == 4 || p == 5) ? (t0 + 2) * 64 + 32
                                                  : (t0 + 3) * 64;
                    if (koff > DIM - 32) koff = DIM - 32;
                    const int sb = (p <= 1 || p >= 6) ? 1 : 0;
                    const int sh = (p <= 1 || p == 4 || p == 5) ? 1 : 0;
                    if ((p & 1) == 0) stageA(sb, sh, koff);
                    else              stageB(sb, sh, koff);
                }
                __builtin_amdgcn_s_barrier();
                asm volatile("s_waitcnt lgkmcnt(0)" ::: "memory");
                __builtin_amdgcn_s_setprio(1);
                #pragma unroll
                for (int ii = 0; ii < 4; ++ii) {
                    if (FULL || (fh * 4 + ii) < nfw) {
                        #pragma unroll
                        for (int j = 0; j < 4; ++j)
                            acc[fh * 4 + ii][j] = __builtin_amdgcn_mfma_f32_16x16x32_bf16(
                                af[ii], bfr[j], acc[fh * 4 + ii][j], 0, 0, 0);
                    }
                }
                __builtin_amdgcn_s_setprio(0);
                __builtin_amdgcn_s_barrier();
            }
        }
    }
    asm volatile("s_waitcnt vmcnt(0)" ::: "memory");   // drain tail stages

    #pragma unroll
    for (int j = 0; j < 4; ++j) {
        int col = n0 + wn + j * 16 + lr;
        float bv = bias[e * DIM + col];
        #pragma unroll
        for (int i = 0; i < 8; ++i) {
            #pragma unroll
            for (int r = 0; r < 4; ++r) {
                int lrow = wm + i * 16 + quad * 4 + r;
                if (lrow < valid) {
                    out[(size_t)permS[lrow] * DIM + col] = acc[i][j][r] + bv;
                }
            }
        }
    }
}

// ---- GEMM kernel: tile mapping (fulls first, XCD-chunked) ----------------
__global__ __launch_bounds__(512, 2) void k_gemm(
    const uint16_t* __restrict__ xb, const uint16_t* __restrict__ Wt,
    const float* __restrict__ bias, const int* __restrict__ meta,
    const int* __restrict__ perm, float* __restrict__ out) {
    __shared__ uint16_t As[2][2][8192];   // 64KB
    __shared__ uint16_t Bs[2][2][8192];   // 64KB
    __shared__ int permS[BM];             // 1KB

    int nf[NEXP], s0e[NEXP];
    int F = 0;
    #pragma unroll
    for (int i = 0; i < NEXP; ++i) {
        s0e[i] = meta[16 + i];
        int c = meta[17 + i] - s0e[i];
        nf[i] = c >> 8;
        F += nf[i];
    }
    int b = blockIdx.x;
    int e = 0, m0 = 0, valid = 0, bx = 0;
    if (b < F * 8) {
        // full tiles: bijective XCD-chunked map (F*8 % 8 == 0 always)
        int g = (b & 7) * F + (b >> 3);
        int yf = g >> 3; bx = g & 7;
        int a = 0;
        #pragma unroll
        for (int i = 0; i < NEXP; ++i) {
            if (yf >= a && yf < a + nf[i]) { e = i; m0 = s0e[i] + (yf - a) * BM; }
            a += nf[i];
        }
        valid = BM;
    } else {
        int pi = b - F * 8;
        int pe = pi >> 3; bx = pi & 7;
        if (pe >= NEXP) return;
        int c = meta[17 + pe] - meta[16 + pe];
        int rem = c - ((c >> 8) << 8);
        if (rem == 0) return;
        e = pe; m0 = s0e[pe] + (c >> 8) * BM; valid = rem;
    }
    int n0 = bx * BN;
    if (valid == BM)
        gemm_core<true >(As, Bs, permS, xb, Wt, bias, perm, out, e, m0, BM,    n0);
    else
        gemm_core<false>(As, Bs, permS, xb, Wt, bias, perm, out, e, m0, valid, n0);
}

// ---- launch --------------------------------------------------------------
// ws: [0,256) meta | [256,33024) perm | [64K, +33.55MB) xb | Wt 67.1MB.
extern "C" void kernel_launch(void* const* d_in, const int* in_sizes, int n_in,
                              void* d_out, int out_size, void* d_ws, size_t ws_size,
                              hipStream_t stream) {
    const float* x    = (const float*)d_in[0];
    const float* W    = (const float*)d_in[1];
    const float* bias = (const float*)d_in[2];
    const int*   idx  = (const int*)d_in[3];
    float* out = (float*)d_out;

    char* ws = (char*)d_ws;
    int* meta = (int*)ws;
    int* perm = (int*)(ws + 256);
    uint16_t* xb = (uint16_t*)(ws + 65536);
    uint16_t* Wt = (uint16_t*)(ws + 65536 + (size_t)B_TOK * DIM * 2);

    k_prep<<<1 + B_TOK + 4096, 256, 0, stream>>>(x, W, idx, meta, perm, xb, Wt);
    // 320 blocks: <=32*8 full tiles first, then <=8*8 partial tiles.
    k_gemm<<<320, 512, 0, stream>>>(xb, Wt, bias, meta, perm, out);
}

// Round 3
// 387.316 us; speedup vs baseline: 1.1265x; 1.0271x over previous
//
#include <hip/hip_runtime.h>
#include <hip/hip_bf16.h>
#include <stdint.h>

// MoE routed GEMM: out[i] = x[i] @ W[e_i] + b[e_i]
// B=8192, D=2048, E=8. fp32 in/out, bf16 MFMA compute.
// R6: same 8-phase counted-vmcnt schedule as R5 (rotation verified), but
// de-fanged the compiler's hidden waitcnt injection:
//   (1) waitcnt asms have NO "memory" clobber (memory-clobbered asm gets a
//       conservative vmcnt(0)lgkmcnt(0) inserted before it by the backend),
//   (2) LDS fragment reads are volatile inline-asm ds_read_b128 on 32-bit
//       LDS addresses (no visible alias with global_load_lds dests -> no
//       injected vmcnt waits),
//   (3) rule #18: sched_barrier(0) right after each lgkmcnt(0) so MFMAs
//       can't hoist above the wait.
// Addressing/swizzle/rotation byte-identical to R5 (passed, 0 conflicts).

#define B_TOK 8192
#define DIM   2048
#define NEXP  8
#define BM 256
#define BN 256
#define BK 64

typedef __attribute__((ext_vector_type(4))) float f32x4;
typedef __attribute__((ext_vector_type(8))) short s16x8;
typedef __attribute__((address_space(3))) uint16_t lds_u16;

// RNE float->bf16
__device__ __forceinline__ uint32_t f2bf(float f) {
    uint32_t u = __float_as_uint(f);
    uint32_t r = u + 0x7fffu + ((u >> 16) & 1u);
    return r >> 16;
}

__device__ __forceinline__ void async16(const void* g, void* l) {
    __builtin_amdgcn_global_load_lds(
        (const __attribute__((address_space(1))) uint32_t*)g,
        (__attribute__((address_space(3))) uint32_t*)l, 16, 0, 0);
}

#define DSR(dst, a) asm volatile("ds_read_b128 %0, %1" : "=v"(dst) : "v"(a))

// ---- prep: block 0 = routing; blocks 1..8192 = x fp32->bf16 (unsorted);
// ---- blocks 8193..12288 = W[e][d][o] -> Wt[e][o][d] bf16 transpose.
__global__ __launch_bounds__(256) void k_prep(const float* __restrict__ x,
                                              const float* __restrict__ W,
                                              const int* __restrict__ idx,
                                              int* __restrict__ meta,
                                              int* __restrict__ perm,
                                              uint16_t* __restrict__ xb,
                                              uint16_t* __restrict__ Wt) {
    __shared__ __align__(16) char smem[16640];   // max(route 9252, wt 16640)
    int bid = blockIdx.x;
    int t = threadIdx.x;

    if (bid == 0) {
        // ---- routing: zero atomics, deterministic ----
        int (*cnt)[9] = (int(*)[9])smem;          // 256*9*4 = 9216
        int* offS = (int*)(smem + 9216);          // 9*4
        int myIdx[32];
        #pragma unroll
        for (int i = 0; i < 32; ++i) myIdx[i] = idx[t * 32 + i];
        int c[NEXP] = {0, 0, 0, 0, 0, 0, 0, 0};
        #pragma unroll
        for (int i = 0; i < 32; ++i) {
            int e = myIdx[i];
            #pragma unroll
            for (int k = 0; k < NEXP; ++k) c[k] += (e == k) ? 1 : 0;
        }
        #pragma unroll
        for (int k = 0; k < NEXP; ++k) cnt[t][k] = c[k];
        __syncthreads();
        if (t < NEXP) {                 // 8 threads: exclusive scan down column t
            int run = 0;
            for (int j = 0; j < 256; ++j) { int v = cnt[j][t]; cnt[j][t] = run; run += v; }
            offS[t] = run;
        }
        __syncthreads();
        if (t == 0) {
            int off = 0;
            #pragma unroll
            for (int e = 0; e < NEXP; ++e) {
                int v = offS[e];
                offS[e] = off; meta[16 + e] = off; off += v;
            }
            offS[NEXP] = off; meta[16 + NEXP] = off;
        }
        __syncthreads();
        int base[NEXP];
        #pragma unroll
        for (int k = 0; k < NEXP; ++k) base[k] = offS[k] + cnt[t][k];
        #pragma unroll
        for (int i = 0; i < 32; ++i) {
            int e = myIdx[i];
            int pos = 0;
            #pragma unroll
            for (int k = 0; k < NEXP; ++k) pos += (e == k) ? base[k] : 0;
            perm[pos] = t * 32 + i;
            #pragma unroll
            for (int k = 0; k < NEXP; ++k) base[k] += (e == k) ? 1 : 0;
        }
        return;
    }

    if (bid <= B_TOK) {
        // ---- x convert, original row order ----
        int p = bid - 1;
        const float4* xin = (const float4*)(x + (size_t)p * DIM);
        float4 a = xin[2 * t];
        float4 c = xin[2 * t + 1];
        uint4 o;
        o.x = f2bf(a.x) | (f2bf(a.y) << 16);
        o.y = f2bf(a.z) | (f2bf(a.w) << 16);
        o.z = f2bf(c.x) | (f2bf(c.y) << 16);
        o.w = f2bf(c.z) | (f2bf(c.w) << 16);
        *(uint4*)(xb + (size_t)p * DIM + t * 8) = o;
        return;
    }

    // ---- W transpose tile 128d x 64o ----
    int wb = bid - (B_TOK + 1);
    int bx = wb & 15, by = (wb >> 4) & 31, e = wb >> 9;
    int d0 = bx * 128, o0 = by * 64;
    uint32_t (*lds)[65] = (uint32_t(*)[65])smem;
    const float* Wp = W + ((size_t)e * DIM + d0) * DIM + o0;
    #pragma unroll
    for (int p = 0; p < 4; ++p) {
        int dp = p * 16 + (t >> 4);      // d-pair index 0..63
        int oc = (t & 15) * 4;           // o base
        const float* r0 = Wp + (size_t)(2 * dp) * DIM + oc;
        float4 v0 = *(const float4*)r0;
        float4 v1 = *(const float4*)(r0 + DIM);
        lds[oc + 0][dp ^ (((oc + 0) & 15) << 2)] = f2bf(v0.x) | (f2bf(v1.x) << 16);
        lds[oc + 1][dp ^ (((oc + 1) & 15) << 2)] = f2bf(v0.y) | (f2bf(v1.y) << 16);
        lds[oc + 2][dp ^ (((oc + 2) & 15) << 2)] = f2bf(v0.z) | (f2bf(v1.z) << 16);
        lds[oc + 3][dp ^ (((oc + 3) & 15) << 2)] = f2bf(v0.w) | (f2bf(v1.w) << 16);
    }
    __syncthreads();
    uint16_t* Wo = Wt + ((size_t)e * DIM + o0) * DIM + d0;
    #pragma unroll
    for (int q = 0; q < 4; ++q) {
        int o = q * 16 + (t >> 4);
        int cb = ((t & 15) * 4) ^ ((o & 15) << 2);
        uint4 w = *(const uint4*)&lds[o][cb];
        *(uint4*)(Wo + (size_t)o * DIM + (t & 15) * 8) = w;
    }
}

// ---- 8-phase GEMM core (R5 rotation; asm ds_read; clean waitcnts) --------
// LDS halves: As/Bs[buf][ksub][256 rows][32 elems] (16KB each).
// Read swizzle: phys 16B-slot = quad ^ ((lr>>1)&3); stage pre-swizzles the
// per-lane GLOBAL source slot (rule #21). Verified conflict-free (R5).
// Rotation (p = tp*4+q): compute p0(m0k0) p1(m1k0) p2(m0k1) p3(m1k1) on
// buf tp; stage p0:A[1][1]@t+1k1 p1:B[1][1] p2:A[0][0]@t+2k0 p3:B[0][0]
// p4:A[0][1]@t+2k1 p5:B[0][1] p6:A[1][0]@t+3k0 p7:B[1][0].
// Every read's operands staged 5-6 phases earlier; vmcnt(6) at odd phases
// retires age-3 stages -> slack. No vmcnt(0) in the loop.
template<bool FULL>
__device__ __forceinline__ void gemm_core(
    uint16_t (*As)[2][8192], uint16_t (*Bs)[2][8192], int* permS,
    const uint16_t* __restrict__ xb, const uint16_t* __restrict__ Wt,
    const float* __restrict__ bias, const int* __restrict__ perm,
    float* __restrict__ out, int e, int m0, int valid, int n0) {

    int tid = threadIdx.x;
    if (tid < BM) permS[tid] = (tid < valid) ? perm[m0 + tid] : 0;

    int wave = tid >> 6, lane = tid & 63;
    int wm = (wave >> 2) * 128, wn = (wave & 3) * 64;
    int lr = lane & 15, quad = lane >> 4;
    const int rdswz = (quad ^ ((lr >> 1) & 3)) * 8;   // element offset in row
    int nfw = 8;
    if (!FULL) { nfw = (valid > wm) ? ((valid - wm + 15) >> 4) : 0; if (nfw > 8) nfw = 8; }

    // 32-bit LDS byte addresses for asm ds_read (backend sees no LDS alias).
    const uint32_t asA = (uint32_t)(uintptr_t)(lds_u16*)&As[0][0][0];
    const uint32_t asB = (uint32_t)(uintptr_t)(lds_u16*)&Bs[0][0][0];
    const uint32_t aBase = asA + (uint32_t)((wm + lr) * 64 + rdswz * 2);
    const uint32_t bBase = asB + (uint32_t)((wn + lr) * 64 + rdswz * 2);

    // staging sources: chunk ch = c*512+tid -> row = ch>>2, slot = ch&3;
    // source slot = (tid&3) ^ ((tid>>3)&3)  (rule #21 pre-swizzle).
    const int srcswz = (((tid & 3) ^ ((tid >> 3) & 3)) * 8);
    const uint16_t* aPtr[2];
    const uint16_t* bPtr[2];
    #pragma unroll
    for (int c = 0; c < 2; ++c) {
        int row = c * 128 + (tid >> 2);
        int ar = m0 + row; if (ar > B_TOK - 1) ar = B_TOK - 1;
        aPtr[c] = xb + (size_t)perm[ar] * DIM + srcswz;
        bPtr[c] = Wt + ((size_t)e * DIM + n0 + row) * DIM + srcswz;
    }

    auto stageA = [&](int buf, int h, int koff) {
        #pragma unroll
        for (int c = 0; c < 2; ++c)
            async16(aPtr[c] + koff, &As[buf][h][(c * 512 + tid) * 8]);
    };
    auto stageB = [&](int buf, int h, int koff) {
        #pragma unroll
        for (int c = 0; c < 2; ++c)
            async16(bPtr[c] + koff, &Bs[buf][h][(c * 512 + tid) * 8]);
    };

    f32x4 acc[8][4] = {};

    // prologue: tile0 k0,k1 + tile1 k0 (12 loads); need first 4 landed.
    stageA(0, 0, 0);  stageB(0, 0, 0);
    stageA(0, 1, 32); stageB(0, 1, 32);
    stageA(1, 0, 64); stageB(1, 0, 64);
    asm volatile("s_waitcnt vmcnt(8)");
    __builtin_amdgcn_s_barrier();

    for (int it = 0; it < DIM / 128; ++it) {
        int t0 = 2 * it;
        s16x8 bfr[4];
        #pragma unroll
        for (int tp = 0; tp < 2; ++tp) {
            #pragma unroll
            for (int q = 0; q < 4; ++q) {
                const int p = tp * 4 + q;
                const int fh = q & 1, ks = q >> 1;
                if (p & 1) asm volatile("s_waitcnt vmcnt(6)");
                // ds_read current fragments (asm; addresses = base + const)
                const uint32_t hoff = (uint32_t)((tp * 2 + ks) * 16384);
                s16x8 af[4];
                #pragma unroll
                for (int ii = 0; ii < 4; ++ii)
                    DSR(af[ii], aBase + hoff + (uint32_t)((fh * 4 + ii) * 1024));
                if (fh == 0) {
                    #pragma unroll
                    for (int j = 0; j < 4; ++j)
                        DSR(bfr[j], bBase + hoff + (uint32_t)(j * 1024));
                }
                // stage one half per rotation table
                {
                    int koff = (p == 0 || p == 1) ? (t0 + 1) * 64 + 32
                             : (p == 2 || p == 3) ? (t0 + 2) * 64
                             : (p == 4 || p == 5) ? (t0 + 2) * 64 + 32
                                                  : (t0 + 3) * 64;
                    if (koff > DIM - 32) koff = DIM - 32;
                    const int sb = (p <= 1 || p >= 6) ? 1 : 0;
                    const int sh = (p <= 1 || p == 4 || p == 5) ? 1 : 0;
                    if ((p & 1) == 0) stageA(sb, sh, koff);
                    else              stageB(sb, sh, koff);
                }
                __builtin_amdgcn_s_barrier();
                asm volatile("s_waitcnt lgkmcnt(0)");
                __builtin_amdgcn_sched_barrier(0);       // rule #18
                __builtin_amdgcn_s_setprio(1);
                #pragma unroll
                for (int ii = 0; ii < 4; ++ii) {
                    if (FULL || (fh * 4 + ii) < nfw) {
                        #pragma unroll
                        for (int j = 0; j < 4; ++j)
                            acc[fh * 4 + ii][j] = __builtin_amdgcn_mfma_f32_16x16x32_bf16(
                                af[ii], bfr[j], acc[fh * 4 + ii][j], 0, 0, 0);
                    }
                }
                __builtin_amdgcn_s_setprio(0);
                __builtin_amdgcn_s_barrier();
            }
        }
    }
    asm volatile("s_waitcnt vmcnt(0)");   // drain tail stages before exit

    #pragma unroll
    for (int j = 0; j < 4; ++j) {
        int col = n0 + wn + j * 16 + lr;
        float bv = bias[e * DIM + col];
        #pragma unroll
        for (int i = 0; i < 8; ++i) {
            #pragma unroll
            for (int r = 0; r < 4; ++r) {
                int lrow = wm + i * 16 + quad * 4 + r;
                if (lrow < valid) {
                    out[(size_t)permS[lrow] * DIM + col] = acc[i][j][r] + bv;
                }
            }
        }
    }
}

// ---- GEMM kernel: tile mapping (fulls first, XCD-chunked) ----------------
__global__ __launch_bounds__(512, 2) void k_gemm(
    const uint16_t* __restrict__ xb, const uint16_t* __restrict__ Wt,
    const float* __restrict__ bias, const int* __restrict__ meta,
    const int* __restrict__ perm, float* __restrict__ out) {
    __shared__ uint16_t As[2][2][8192];   // 64KB
    __shared__ uint16_t Bs[2][2][8192];   // 64KB
    __shared__ int permS[BM];             // 1KB

    int nf[NEXP], s0e[NEXP];
    int F = 0;
    #pragma unroll
    for (int i = 0; i < NEXP; ++i) {
        s0e[i] = meta[16 + i];
        int c = meta[17 + i] - s0e[i];
        nf[i] = c >> 8;
        F += nf[i];
    }
    int b = blockIdx.x;
    int e = 0, m0 = 0, valid = 0, bx = 0;
    if (b < F * 8) {
        // full tiles: bijective XCD-chunked map (F*8 % 8 == 0 always)
        int g = (b & 7) * F + (b >> 3);
        int yf = g >> 3; bx = g & 7;
        int a = 0;
        #pragma unroll
        for (int i = 0; i < NEXP; ++i) {
            if (yf >= a && yf < a + nf[i]) { e = i; m0 = s0e[i] + (yf - a) * BM; }
            a += nf[i];
        }
        valid = BM;
    } else {
        int pi = b - F * 8;
        int pe = pi >> 3; bx = pi & 7;
        if (pe >= NEXP) return;
        int c = meta[17 + pe] - meta[16 + pe];
        int rem = c - ((c >> 8) << 8);
        if (rem == 0) return;
        e = pe; m0 = s0e[pe] + (c >> 8) * BM; valid = rem;
    }
    int n0 = bx * BN;
    if (valid == BM)
        gemm_core<true >(As, Bs, permS, xb, Wt, bias, perm, out, e, m0, BM,    n0);
    else
        gemm_core<false>(As, Bs, permS, xb, Wt, bias, perm, out, e, m0, valid, n0);
}

// ---- launch --------------------------------------------------------------
// ws: [0,256) meta | [256,33024) perm | [64K, +33.55MB) xb | Wt 67.1MB.
extern "C" void kernel_launch(void* const* d_in, const int* in_sizes, int n_in,
                              void* d_out, int out_size, void* d_ws, size_t ws_size,
                              hipStream_t stream) {
    const float* x    = (const float*)d_in[0];
    const float* W    = (const float*)d_in[1];
    const float* bias = (const float*)d_in[2];
    const int*   idx  = (const int*)d_in[3];
    float* out = (float*)d_out;

    char* ws = (char*)d_ws;
    int* meta = (int*)ws;
    int* perm = (int*)(ws + 256);
    uint16_t* xb = (uint16_t*)(ws + 65536);
    uint16_t* Wt = (uint16_t*)(ws + 65536 + (size_t)B_TOK * DIM * 2);

    k_prep<<<1 + B_TOK + 4096, 256, 0, stream>>>(x, W, idx, meta, perm, xb, Wt);
    // 320 blocks: <=32*8 full tiles first, then <=8*8 partial tiles.
    k_gemm<<<320, 512, 0, stream>>>(xb, Wt, bias, meta, perm, out);
}